// Round 2
// baseline (628.118 us; speedup 1.0000x reference)
//
#include <hip/hip_runtime.h>
#include <math.h>

#define EMB 256

// Column swizzle: XOR bits 2-4 of the LDS column with ((c>>5)&1)^((k>>1)&7).
// - keeps float4 groups contiguous (only bits>=2 touched, c>>5 uniform per group)
// - staging writes (k = quad base + j, col varies per lane): exactly 2-way -> free
// - B-fragment reads (k uniform, col = tx*8): spreads {0,8,16,24} bank pattern
//   across all 32 banks -> 2-way -> free
__device__ __forceinline__ int swz(int c, int k) {
    return c ^ ((((c >> 5) & 1) ^ ((k >> 1) & 7)) << 2);
}

// Fused: computes H = X*Wh^T + bh (grid.y 0,1) and T = X*Wt^T + bt (grid.y 2,3).
// BM=256, BN=128, BK=32, 512 threads, 8x8 per-thread tile, reg-prefetch next k-tile.
__global__ __launch_bounds__(512, 4)
void gemm_fused(const float* __restrict__ X,
                const float* __restrict__ Wh, const float* __restrict__ bh,
                const float* __restrict__ Wt, const float* __restrict__ bt,
                float* __restrict__ Hout, float* __restrict__ Tout, int M)
{
    __shared__ float xs[32][260];   // k-major X tile, stride 260 (== 4 mod 32)
    __shared__ float ws[32][132];   // k-major W tile, stride 132 (== 4 mod 32)

    const int tid = threadIdx.x;
    const int y = blockIdx.y;
    const float* __restrict__ W    = (y < 2) ? Wh : Wt;
    const float* __restrict__ bias = (y < 2) ? bh : bt;
    float* __restrict__ OUT        = (y < 2) ? Hout : Tout;
    const int n0 = (y & 1) << 7;       // 0 or 128
    const int m0 = blockIdx.x << 8;    // * 256

    const int tx = tid & 15;           // n octet
    const int ty = tid >> 4;           // m octet 0..31
    const int f4 = tid & 7;            // k-quad in BK=32
    const int r0 = tid >> 3;           // 0..63 (staging row)
    const int kq = f4 << 2;            // k base of this thread's quad

    float acc[8][8];
#pragma unroll
    for (int i = 0; i < 8; ++i)
#pragma unroll
        for (int j = 0; j < 8; ++j) acc[i][j] = 0.f;

    float4 xg[4], wg[2];
#pragma unroll
    for (int p = 0; p < 4; ++p) {
        const int gm = m0 + r0 + p * 64;
        xg[p] = (gm < M) ? *(const float4*)&X[(size_t)gm * EMB + kq]
                         : make_float4(0.f, 0.f, 0.f, 0.f);
    }
#pragma unroll
    for (int p = 0; p < 2; ++p)
        wg[p] = *(const float4*)&W[(size_t)(n0 + r0 + p * 64) * EMB + kq];

    for (int k0 = 0; k0 < EMB; k0 += 32) {
        __syncthreads();   // previous compute done before overwriting LDS
#pragma unroll
        for (int p = 0; p < 4; ++p) {
            const int c = r0 + p * 64;
            xs[kq + 0][swz(c, kq + 0)] = xg[p].x;
            xs[kq + 1][swz(c, kq + 1)] = xg[p].y;
            xs[kq + 2][swz(c, kq + 2)] = xg[p].z;
            xs[kq + 3][swz(c, kq + 3)] = xg[p].w;
        }
#pragma unroll
        for (int p = 0; p < 2; ++p) {
            const int c = r0 + p * 64;
            ws[kq + 0][swz(c, kq + 0)] = wg[p].x;
            ws[kq + 1][swz(c, kq + 1)] = wg[p].y;
            ws[kq + 2][swz(c, kq + 2)] = wg[p].z;
            ws[kq + 3][swz(c, kq + 3)] = wg[p].w;
        }
        __syncthreads();

        // prefetch next k-tile into registers; drains only at next loop-top write
        if (k0 + 32 < EMB) {
            const int kn = k0 + 32 + kq;
#pragma unroll
            for (int p = 0; p < 4; ++p) {
                const int gm = m0 + r0 + p * 64;
                xg[p] = (gm < M) ? *(const float4*)&X[(size_t)gm * EMB + kn]
                                 : make_float4(0.f, 0.f, 0.f, 0.f);
            }
#pragma unroll
            for (int p = 0; p < 2; ++p)
                wg[p] = *(const float4*)&W[(size_t)(n0 + r0 + p * 64) * EMB + kn];
        }

#pragma unroll 4
        for (int kk = 0; kk < 32; ++kk) {
            const float4 a0 = *(const float4*)&xs[kk][swz(ty * 8, kk)];
            const float4 a1 = *(const float4*)&xs[kk][swz(ty * 8 + 4, kk)];
            const float4 b0 = *(const float4*)&ws[kk][swz(tx * 8, kk)];
            const float4 b1 = *(const float4*)&ws[kk][swz(tx * 8 + 4, kk)];
            const float a[8] = {a0.x, a0.y, a0.z, a0.w, a1.x, a1.y, a1.z, a1.w};
            const float b[8] = {b0.x, b0.y, b0.z, b0.w, b1.x, b1.y, b1.z, b1.w};
#pragma unroll
            for (int i = 0; i < 8; ++i)
#pragma unroll
                for (int j = 0; j < 8; ++j)
                    acc[i][j] += a[i] * b[j];
        }
    }

    float bn[8];
#pragma unroll
    for (int j = 0; j < 8; ++j) bn[j] = bias[n0 + tx * 8 + j];

#pragma unroll
    for (int i = 0; i < 8; ++i) {
        const int gm = m0 + ty * 8 + i;
        if (gm < M) {
            float4 o0, o1;
            o0.x = acc[i][0] + bn[0]; o0.y = acc[i][1] + bn[1];
            o0.z = acc[i][2] + bn[2]; o0.w = acc[i][3] + bn[3];
            o1.x = acc[i][4] + bn[4]; o1.y = acc[i][5] + bn[5];
            o1.z = acc[i][6] + bn[6]; o1.w = acc[i][7] + bn[7];
            float* dst = &OUT[(size_t)gm * EMB + n0 + tx * 8];
            *(float4*)dst = o0;
            *(float4*)(dst + 4) = o1;
        }
    }
}

// One wave per edge: gather H[src], T[dst], rel[type], triple-product reduce, sigmoid.
__global__ __launch_bounds__(256)
void edge_score(const float* __restrict__ H, const float* __restrict__ T,
                const float* __restrict__ rel, const int* __restrict__ ei,
                const int* __restrict__ et, float* __restrict__ out, int E)
{
    const int lane = threadIdx.x & 63;
    const int wid = threadIdx.x >> 6;
    const int e = blockIdx.x * 4 + wid;
    if (e >= E) return;

    const int src = ei[e];
    const int dst = ei[E + e];
    const int r = et[e];

    const float4 h = *(const float4*)&H[(size_t)src * EMB + lane * 4];
    const float4 t = *(const float4*)&T[(size_t)dst * EMB + lane * 4];
    const float4 g = *(const float4*)&rel[(size_t)r * EMB + lane * 4];

    float s = h.x * g.x * t.x + h.y * g.y * t.y + h.z * g.z * t.z + h.w * g.w * t.w;
#pragma unroll
    for (int off = 32; off > 0; off >>= 1)
        s += __shfl_xor(s, off, 64);

    if (lane == 0) out[e] = 1.0f / (1.0f + expf(-s));
}

// Fallback (only if ws too small): one block per edge, direct matvecs.
__global__ __launch_bounds__(256)
void edge_direct(const float* __restrict__ X, const int* __restrict__ ei,
                 const int* __restrict__ et,
                 const float* __restrict__ Wh, const float* __restrict__ bh,
                 const float* __restrict__ Wt, const float* __restrict__ bt,
                 const float* __restrict__ rel, float* __restrict__ out, int E)
{
    __shared__ float xsrc[EMB], xdst[EMB];
    __shared__ float red[256];
    const int e = blockIdx.x;
    const int tid = threadIdx.x;
    const int src = ei[e], dst = ei[E + e], r = et[e];

    xsrc[tid] = X[(size_t)src * EMB + tid];
    xdst[tid] = X[(size_t)dst * EMB + tid];
    __syncthreads();

    float ah = 0.f, at = 0.f;
    const float* wh = Wh + (size_t)tid * EMB;
    const float* wt = Wt + (size_t)tid * EMB;
#pragma unroll 8
    for (int k = 0; k < EMB; k += 4) {
        float4 w4 = *(const float4*)&wh[k];
        ah += w4.x * xsrc[k] + w4.y * xsrc[k + 1] + w4.z * xsrc[k + 2] + w4.w * xsrc[k + 3];
        float4 v4 = *(const float4*)&wt[k];
        at += v4.x * xdst[k] + v4.y * xdst[k + 1] + v4.z * xdst[k + 2] + v4.w * xdst[k + 3];
    }
    red[tid] = (ah + bh[tid]) * rel[(size_t)r * EMB + tid] * (at + bt[tid]);
    __syncthreads();
    for (int s2 = 128; s2 > 0; s2 >>= 1) {
        if (tid < s2) red[tid] += red[tid + s2];
        __syncthreads();
    }
    if (tid == 0) out[e] = 1.0f / (1.0f + expf(-red[0]));
}

extern "C" void kernel_launch(void* const* d_in, const int* in_sizes, int n_in,
                              void* d_out, int out_size, void* d_ws, size_t ws_size,
                              hipStream_t stream) {
    const float* x   = (const float*)d_in[0];
    const int*   ei  = (const int*)d_in[1];
    const int*   et  = (const int*)d_in[2];
    const float* Wh  = (const float*)d_in[3];
    const float* bh  = (const float*)d_in[4];
    const float* Wt  = (const float*)d_in[5];
    const float* bt  = (const float*)d_in[6];
    const float* rel = (const float*)d_in[7];
    float* out = (float*)d_out;

    const int M = in_sizes[0] / EMB;   // 100000 nodes
    const int E = in_sizes[2];         // 250000 edges

    const size_t need = (size_t)2 * M * EMB * sizeof(float);
    if (ws_size >= need) {
        float* H = (float*)d_ws;
        float* T = H + (size_t)M * EMB;
        dim3 grid((M + 255) / 256, 4);
        gemm_fused<<<grid, 512, 0, stream>>>(x, Wh, bh, Wt, bt, H, T, M);
        edge_score<<<(E + 3) / 4, 256, 0, stream>>>(H, T, rel, ei, et, out, E);
    } else {
        edge_direct<<<E, 256, 0, stream>>>(x, ei, et, Wh, bh, Wt, bt, rel, out, E);
    }
}

// Round 3
// 460.257 us; speedup vs baseline: 1.3647x; 1.3647x over previous
//
#include <hip/hip_runtime.h>
#include <math.h>

#define EMB 256

// Column swizzle: XOR bits 2-4 of the LDS column with ((c>>5)&1)^((k>>1)&7).
// With row stride 132 floats (== 4 mod 32 banks), this makes:
//  - staging writes exactly 2-way bank aliasing (free on CDNA4, m136)
//  - B-fragment reads (col = tx*8) 2-way (was 4-way)
//  - A-fragment reads stay wave broadcasts (same address per ty group)
__device__ __forceinline__ int swz(int c, int k) {
    return c ^ ((((c >> 5) & 1) ^ ((k >> 1) & 7)) << 2);
}

// OUT[m][n] = sum_k X[m][k] * W[n][k] + bias[n]
// X: [M][EMB] row-major, W: [256][EMB] row-major (nn.Linear), OUT: [M][256]
// Block: 256 threads (16x16), tile BM=128 x BN=128, BK=32, 8x8 per thread.
// launch_bounds(256,2): VGPR budget stays high; acc lives in unified VGPR/AGPR
// file with NO scratch spill (round-1 counters: FETCH==X exactly, WRITE==OUT).
__global__ __launch_bounds__(256, 2)
void gemm_xwT(const float* __restrict__ X, const float* __restrict__ W,
              const float* __restrict__ bias, float* __restrict__ OUT, int M)
{
    __shared__ float xs[32][132];   // k-major, stride 132 (== 4 mod 32 banks)
    __shared__ float wsh[32][132];

    const int tid = threadIdx.x;
    const int m0 = blockIdx.x * 128;
    const int n0 = blockIdx.y * 128;
    const int tx = tid & 15;       // n-dim
    const int ty = tid >> 4;       // m-dim

    float acc[8][8];
#pragma unroll
    for (int i = 0; i < 8; ++i)
#pragma unroll
        for (int j = 0; j < 8; ++j) acc[i][j] = 0.0f;

    const int f4   = tid & 7;      // k-quad (BK=32 -> 8 float4)
    const int kq   = f4 * 4;
    const int row0 = tid >> 3;     // 0..31

    for (int k0 = 0; k0 < EMB; k0 += 32) {
        // stage X tile (128 rows x 32 k), transposed+swizzled into xs[k][m]
#pragma unroll
        for (int p = 0; p < 4; ++p) {
            const int row = row0 + p * 32;
            const int gm = m0 + row;
            float4 v = make_float4(0.f, 0.f, 0.f, 0.f);
            if (gm < M) v = *(const float4*)&X[(size_t)gm * EMB + k0 + kq];
            xs[kq + 0][swz(row, kq + 0)] = v.x;
            xs[kq + 1][swz(row, kq + 1)] = v.y;
            xs[kq + 2][swz(row, kq + 2)] = v.z;
            xs[kq + 3][swz(row, kq + 3)] = v.w;
        }
        // stage W tile (128 rows x 32 k), transposed+swizzled into wsh[k][n]
#pragma unroll
        for (int p = 0; p < 4; ++p) {
            const int row = row0 + p * 32;
            const float4 v = *(const float4*)&W[(size_t)(n0 + row) * EMB + k0 + kq];
            wsh[kq + 0][swz(row, kq + 0)] = v.x;
            wsh[kq + 1][swz(row, kq + 1)] = v.y;
            wsh[kq + 2][swz(row, kq + 2)] = v.z;
            wsh[kq + 3][swz(row, kq + 3)] = v.w;
        }
        __syncthreads();

#pragma unroll 4
        for (int kk = 0; kk < 32; ++kk) {
            const float4 a0 = *(const float4*)&xs[kk][swz(ty * 8, kk)];
            const float4 a1 = *(const float4*)&xs[kk][swz(ty * 8 + 4, kk)];
            const float4 b0 = *(const float4*)&wsh[kk][swz(tx * 8, kk)];
            const float4 b1 = *(const float4*)&wsh[kk][swz(tx * 8 + 4, kk)];
            const float a[8] = {a0.x, a0.y, a0.z, a0.w, a1.x, a1.y, a1.z, a1.w};
            const float b[8] = {b0.x, b0.y, b0.z, b0.w, b1.x, b1.y, b1.z, b1.w};
#pragma unroll
            for (int i = 0; i < 8; ++i)
#pragma unroll
                for (int j = 0; j < 8; ++j)
                    acc[i][j] += a[i] * b[j];
        }
        __syncthreads();
    }

    float bn[8];
#pragma unroll
    for (int j = 0; j < 8; ++j) bn[j] = bias[n0 + tx * 8 + j];

#pragma unroll
    for (int i = 0; i < 8; ++i) {
        const int gm = m0 + ty * 8 + i;
        if (gm < M) {
            float4 o0, o1;
            o0.x = acc[i][0] + bn[0]; o0.y = acc[i][1] + bn[1];
            o0.z = acc[i][2] + bn[2]; o0.w = acc[i][3] + bn[3];
            o1.x = acc[i][4] + bn[4]; o1.y = acc[i][5] + bn[5];
            o1.z = acc[i][6] + bn[6]; o1.w = acc[i][7] + bn[7];
            float* dst = &OUT[(size_t)gm * EMB + n0 + tx * 8];
            *(float4*)dst = o0;
            *(float4*)(dst + 4) = o1;
        }
    }
}

// One wave per edge: gather H[src], T[dst], rel[type], triple-product reduce, sigmoid.
__global__ __launch_bounds__(256)
void edge_score(const float* __restrict__ H, const float* __restrict__ T,
                const float* __restrict__ rel, const int* __restrict__ ei,
                const int* __restrict__ et, float* __restrict__ out, int E)
{
    const int lane = threadIdx.x & 63;
    const int wid = threadIdx.x >> 6;
    const int e = blockIdx.x * 4 + wid;
    if (e >= E) return;

    const int src = ei[e];
    const int dst = ei[E + e];
    const int r = et[e];

    const float4 h = *(const float4*)&H[(size_t)src * EMB + lane * 4];
    const float4 t = *(const float4*)&T[(size_t)dst * EMB + lane * 4];
    const float4 g = *(const float4*)&rel[(size_t)r * EMB + lane * 4];

    float s = h.x * g.x * t.x + h.y * g.y * t.y + h.z * g.z * t.z + h.w * g.w * t.w;
#pragma unroll
    for (int off = 32; off > 0; off >>= 1)
        s += __shfl_xor(s, off, 64);

    if (lane == 0) out[e] = 1.0f / (1.0f + expf(-s));
}

// Fallback (only if ws too small): one block per edge, direct matvecs.
__global__ __launch_bounds__(256)
void edge_direct(const float* __restrict__ X, const int* __restrict__ ei,
                 const int* __restrict__ et,
                 const float* __restrict__ Wh, const float* __restrict__ bh,
                 const float* __restrict__ Wt, const float* __restrict__ bt,
                 const float* __restrict__ rel, float* __restrict__ out, int E)
{
    __shared__ float xsrc[EMB], xdst[EMB];
    __shared__ float red[256];
    const int e = blockIdx.x;
    const int tid = threadIdx.x;
    const int src = ei[e], dst = ei[E + e], r = et[e];

    xsrc[tid] = X[(size_t)src * EMB + tid];
    xdst[tid] = X[(size_t)dst * EMB + tid];
    __syncthreads();

    float ah = 0.f, at = 0.f;
    const float* wh = Wh + (size_t)tid * EMB;
    const float* wt = Wt + (size_t)tid * EMB;
#pragma unroll 8
    for (int k = 0; k < EMB; k += 4) {
        float4 w4 = *(const float4*)&wh[k];
        ah += w4.x * xsrc[k] + w4.y * xsrc[k + 1] + w4.z * xsrc[k + 2] + w4.w * xsrc[k + 3];
        float4 v4 = *(const float4*)&wt[k];
        at += v4.x * xdst[k] + v4.y * xdst[k + 1] + v4.z * xdst[k + 2] + v4.w * xdst[k + 3];
    }
    red[tid] = (ah + bh[tid]) * rel[(size_t)r * EMB + tid] * (at + bt[tid]);
    __syncthreads();
    for (int s2 = 128; s2 > 0; s2 >>= 1) {
        if (tid < s2) red[tid] += red[tid + s2];
        __syncthreads();
    }
    if (tid == 0) out[e] = 1.0f / (1.0f + expf(-red[0]));
}

extern "C" void kernel_launch(void* const* d_in, const int* in_sizes, int n_in,
                              void* d_out, int out_size, void* d_ws, size_t ws_size,
                              hipStream_t stream) {
    const float* x   = (const float*)d_in[0];
    const int*   ei  = (const int*)d_in[1];
    const int*   et  = (const int*)d_in[2];
    const float* Wh  = (const float*)d_in[3];
    const float* bh  = (const float*)d_in[4];
    const float* Wt  = (const float*)d_in[5];
    const float* bt  = (const float*)d_in[6];
    const float* rel = (const float*)d_in[7];
    float* out = (float*)d_out;

    const int M = in_sizes[0] / EMB;   // 100000 nodes
    const int E = in_sizes[2];         // 250000 edges

    const size_t need = (size_t)2 * M * EMB * sizeof(float);
    if (ws_size >= need) {
        float* H = (float*)d_ws;
        float* T = H + (size_t)M * EMB;
        dim3 grid((M + 127) / 128, EMB / 128);
        gemm_xwT<<<grid, 256, 0, stream>>>(x, Wh, bh, H, M);
        gemm_xwT<<<grid, 256, 0, stream>>>(x, Wt, bt, T, M);
        edge_score<<<(E + 3) / 4, 256, 0, stream>>>(H, T, rel, ei, et, out, E);
    } else {
        edge_direct<<<E, 256, 0, stream>>>(x, ei, et, Wh, bh, Wt, bt, rel, out, E);
    }
}

// Round 4
// 217.359 us; speedup vs baseline: 2.8898x; 2.1175x over previous
//
#include <hip/hip_runtime.h>
#include <math.h>

#define EMB 256

typedef _Float16 half8 __attribute__((ext_vector_type(8)));
typedef _Float16 half4v __attribute__((ext_vector_type(4)));
typedef float f32x4 __attribute__((ext_vector_type(4)));

// fp32 -> hi + lo fp16 split (RNE both steps): x ≈ hi + lo to ~2^-22 rel.
__device__ __forceinline__ void split2(const float4 v, half4v& hi, half4v& lo) {
    hi[0] = (_Float16)v.x; hi[1] = (_Float16)v.y;
    hi[2] = (_Float16)v.z; hi[3] = (_Float16)v.w;
    lo[0] = (_Float16)(v.x - (float)hi[0]);
    lo[1] = (_Float16)(v.y - (float)hi[1]);
    lo[2] = (_Float16)(v.z - (float)hi[2]);
    lo[3] = (_Float16)(v.w - (float)hi[3]);
}

// OUT[m][n] = sum_k X[m][k]*W[n][k] + bias[n], via split fp16 MFMA:
// hi*hi + hi*lo + lo*hi (lo*lo ~2^-22, dropped). Accumulate fp32 in MFMA.
// blockIdx.x: bit0 = n-block (0/128), bit1 = which W (head/tail).
// blockIdx.x is fastest-varying -> 4 variants of one m-tile are dispatch-adjacent
// -> X tile fetched from HBM once, served from L2/L3 for the other 3.
// LDS tiles [row][64 halfs: hi k0..31 | lo k0..31], 128B rows, granule-XOR
// swizzle byte ^= (row&7)<<4 (guide-validated G4 recipe): frag reads 2-way = free.
__global__ __launch_bounds__(256, 2)
void gemm_split_mfma(const float* __restrict__ X,
                     const float* __restrict__ Wh, const float* __restrict__ bh,
                     const float* __restrict__ Wt, const float* __restrict__ bt,
                     float* __restrict__ Hout, float* __restrict__ Tout, int M)
{
    __shared__ __align__(16) _Float16 Ab[128 * 64];   // 16 KB
    __shared__ __align__(16) _Float16 Bb[128 * 64];   // 16 KB

    const int tid = threadIdx.x;
    const int sel = blockIdx.x >> 1;
    const int n0  = (blockIdx.x & 1) << 7;
    const int m0  = blockIdx.y << 7;
    const float* __restrict__ Wsel = sel ? Wt : Wh;
    const float* __restrict__ bsel = sel ? bt : bh;
    float* __restrict__ OUT = sel ? Tout : Hout;

    const int lane = tid & 63;
    const int wv = tid >> 6;           // wave 0..3
    const int wm = (wv >> 1) << 6;     // 0 or 64 (m offset)
    const int wn = (wv & 1) << 6;      // 0 or 64 (n offset)
    const int l15 = lane & 15, l4 = lane >> 4;

    // staging coords: thread covers f32-quad q of BK=32, rows srow+32p
    const int q    = tid & 7;
    const int srow = tid >> 3;         // 0..31
    const int ghi  = q >> 1;           // 16B granule 0..3 (hi); +4 for lo
    const int wby  = (q & 1) << 3;     // byte offset within granule

    f32x4 acc[4][4];
#pragma unroll
    for (int i = 0; i < 4; ++i)
#pragma unroll
        for (int j = 0; j < 4; ++j) acc[i][j] = (f32x4){0.f, 0.f, 0.f, 0.f};

    float4 xg[4], wg[4];
#pragma unroll
    for (int p = 0; p < 4; ++p) {
        const int r = srow + p * 32;
        const int gm = m0 + r;
        xg[p] = (gm < M) ? *(const float4*)&X[(size_t)gm * EMB + q * 4]
                         : make_float4(0.f, 0.f, 0.f, 0.f);
        wg[p] = *(const float4*)&Wsel[(size_t)(n0 + r) * EMB + q * 4];
    }

    for (int k0 = 0; k0 < EMB; k0 += 32) {
        __syncthreads();   // previous tile's frag reads done before overwrite
#pragma unroll
        for (int p = 0; p < 4; ++p) {
            const int r = srow + p * 32;
            const int r7 = r & 7;
            half4v hi, lo;
            split2(xg[p], hi, lo);
            char* abase = (char*)Ab + r * 128 + wby;
            *(half4v*)(abase + (((ghi    ) ^ r7) << 4)) = hi;
            *(half4v*)(abase + (((ghi + 4) ^ r7) << 4)) = lo;
            split2(wg[p], hi, lo);
            char* bbase = (char*)Bb + r * 128 + wby;
            *(half4v*)(bbase + (((ghi    ) ^ r7) << 4)) = hi;
            *(half4v*)(bbase + (((ghi + 4) ^ r7) << 4)) = lo;
        }
        __syncthreads();

        // reg-prefetch next k-tile (drains at next loop-top writes)
        if (k0 + 32 < EMB) {
            const int kn = k0 + 32 + q * 4;
#pragma unroll
            for (int p = 0; p < 4; ++p) {
                const int r = srow + p * 32;
                const int gm = m0 + r;
                xg[p] = (gm < M) ? *(const float4*)&X[(size_t)gm * EMB + kn]
                                 : make_float4(0.f, 0.f, 0.f, 0.f);
                wg[p] = *(const float4*)&Wsel[(size_t)(n0 + r) * EMB + kn];
            }
        }

        // A fragments: m = wm + f*16 + (lane&15), k-run = (lane>>4)*8..+7
        half8 ah[4], al[4];
#pragma unroll
        for (int f = 0; f < 4; ++f) {
            const int m = wm + f * 16 + l15;
            const char* arow = (const char*)Ab + m * 128;
            ah[f] = *(const half8*)(arow + (((l4    ) ^ (m & 7)) << 4));
            al[f] = *(const half8*)(arow + (((l4 + 4) ^ (m & 7)) << 4));
        }
#pragma unroll
        for (int j = 0; j < 4; ++j) {
            const int n = wn + j * 16 + l15;
            const char* brow = (const char*)Bb + n * 128;
            const half8 bhv = *(const half8*)(brow + (((l4    ) ^ (n & 7)) << 4));
            const half8 blv = *(const half8*)(brow + (((l4 + 4) ^ (n & 7)) << 4));
#pragma unroll
            for (int i = 0; i < 4; ++i) {
                acc[i][j] = __builtin_amdgcn_mfma_f32_16x16x32_f16(ah[i], bhv, acc[i][j], 0, 0, 0);
                acc[i][j] = __builtin_amdgcn_mfma_f32_16x16x32_f16(ah[i], blv, acc[i][j], 0, 0, 0);
                acc[i][j] = __builtin_amdgcn_mfma_f32_16x16x32_f16(al[i], bhv, acc[i][j], 0, 0, 0);
            }
        }
    }

    // epilogue: C/D layout col = lane&15, row = (lane>>4)*4 + reg (guide m89)
#pragma unroll
    for (int i = 0; i < 4; ++i) {
        const int rbase = m0 + wm + i * 16 + l4 * 4;
#pragma unroll
        for (int rg = 0; rg < 4; ++rg) {
            const int gr = rbase + rg;
            if (gr < M) {
                float* dst = &OUT[(size_t)gr * EMB + n0 + wn];
#pragma unroll
                for (int j = 0; j < 4; ++j) {
                    const int col = j * 16 + l15;
                    dst[col] = acc[i][j][rg] + bsel[n0 + wn + col];
                }
            }
        }
    }
}

// One wave per edge: gather H[src], T[dst], rel[type], triple-product reduce, sigmoid.
__global__ __launch_bounds__(256)
void edge_score(const float* __restrict__ H, const float* __restrict__ T,
                const float* __restrict__ rel, const int* __restrict__ ei,
                const int* __restrict__ et, float* __restrict__ out, int E)
{
    const int lane = threadIdx.x & 63;
    const int wid = threadIdx.x >> 6;
    const int e = blockIdx.x * 4 + wid;
    if (e >= E) return;

    const int src = ei[e];
    const int dst = ei[E + e];
    const int r = et[e];

    const float4 h = *(const float4*)&H[(size_t)src * EMB + lane * 4];
    const float4 t = *(const float4*)&T[(size_t)dst * EMB + lane * 4];
    const float4 g = *(const float4*)&rel[(size_t)r * EMB + lane * 4];

    float s = h.x * g.x * t.x + h.y * g.y * t.y + h.z * g.z * t.z + h.w * g.w * t.w;
#pragma unroll
    for (int off = 32; off > 0; off >>= 1)
        s += __shfl_xor(s, off, 64);

    if (lane == 0) out[e] = 1.0f / (1.0f + expf(-s));
}

// Fallback (only if ws too small): one block per edge, direct fp32 matvecs.
__global__ __launch_bounds__(256)
void edge_direct(const float* __restrict__ X, const int* __restrict__ ei,
                 const int* __restrict__ et,
                 const float* __restrict__ Wh, const float* __restrict__ bh,
                 const float* __restrict__ Wt, const float* __restrict__ bt,
                 const float* __restrict__ rel, float* __restrict__ out, int E)
{
    __shared__ float xsrc[EMB], xdst[EMB];
    __shared__ float red[256];
    const int e = blockIdx.x;
    const int tid = threadIdx.x;
    const int src = ei[e], dst = ei[E + e], r = et[e];

    xsrc[tid] = X[(size_t)src * EMB + tid];
    xdst[tid] = X[(size_t)dst * EMB + tid];
    __syncthreads();

    float ah = 0.f, at = 0.f;
    const float* wh = Wh + (size_t)tid * EMB;
    const float* wt = Wt + (size_t)tid * EMB;
#pragma unroll 8
    for (int k = 0; k < EMB; k += 4) {
        float4 w4 = *(const float4*)&wh[k];
        ah += w4.x * xsrc[k] + w4.y * xsrc[k + 1] + w4.z * xsrc[k + 2] + w4.w * xsrc[k + 3];
        float4 v4 = *(const float4*)&wt[k];
        at += v4.x * xdst[k] + v4.y * xdst[k + 1] + v4.z * xdst[k + 2] + v4.w * xdst[k + 3];
    }
    red[tid] = (ah + bh[tid]) * rel[(size_t)r * EMB + tid] * (at + bt[tid]);
    __syncthreads();
    for (int s2 = 128; s2 > 0; s2 >>= 1) {
        if (tid < s2) red[tid] += red[tid + s2];
        __syncthreads();
    }
    if (tid == 0) out[e] = 1.0f / (1.0f + expf(-red[0]));
}

extern "C" void kernel_launch(void* const* d_in, const int* in_sizes, int n_in,
                              void* d_out, int out_size, void* d_ws, size_t ws_size,
                              hipStream_t stream) {
    const float* x   = (const float*)d_in[0];
    const int*   ei  = (const int*)d_in[1];
    const int*   et  = (const int*)d_in[2];
    const float* Wh  = (const float*)d_in[3];
    const float* bh  = (const float*)d_in[4];
    const float* Wt  = (const float*)d_in[5];
    const float* bt  = (const float*)d_in[6];
    const float* rel = (const float*)d_in[7];
    float* out = (float*)d_out;

    const int M = in_sizes[0] / EMB;   // 100000 nodes
    const int E = in_sizes[2];         // 250000 edges

    const size_t need = (size_t)2 * M * EMB * sizeof(float);
    if (ws_size >= need) {
        float* H = (float*)d_ws;
        float* T = H + (size_t)M * EMB;
        dim3 grid(4, (M + 127) / 128);
        gemm_split_mfma<<<grid, 256, 0, stream>>>(x, Wh, bh, Wt, bt, H, T, M);
        edge_score<<<(E + 3) / 4, 256, 0, stream>>>(H, T, rel, ei, et, out, E);
    } else {
        edge_direct<<<E, 256, 0, stream>>>(x, ei, et, Wh, bh, Wt, bt, rel, out, E);
    }
}